// Round 9
// baseline (1147.172 us; speedup 1.0000x reference)
//
#include <hip/hip_runtime.h>

// Custom LSTM scan.  B=64, L=512, P=64, A=16, D=512, F=80.
//   h_t = h_{t-1} + tanh(x_t W_ci + b_ci) * sigmoid(h_{t-1} R_ig + b_ig)
//
// R14: ROW-PAIR INTERLEAVE.  R13's batched poll changed nothing (566.9 vs
// 566.1us) -> the ~1750cy/step stall is store-to-visibility latency of
// the sc0sc1 exchange (LLC coherence), a hardware floor.  So fill it:
// each WG-pair handles TWO batch rows (64 WGs of 512thr; q = bid>>5,
// rows 2*(bid&31), +1).  While row A's tagged fetch ages toward
// visibility, the WG computes row B's dots and vice versa; one barrier
// pair serves both rows.  R (register-resident, 32 uint4) is row-
// invariant -> shared.  All 512 threads fetch one dword (tid<256 row A,
// tid>=256 row B).  Per-row math and the A/B-barrier hazard structure
// are exactly R12/R13 (passed, absmax 0.125).
// Exchange protocol (proven R10/R12): tagged dwords (f16(h)<<16 | t+1),
// sc0sc1 system-scope, parity-banked hbuf, zeroed by prep each launch.

#define B_  64
#define L_  512
#define P_  64
#define A_  16
#define D_  512
#define F_  80
#define CI_R 8

#define CI_BYTES   ((size_t)B_ * L_ * D_ * 2)        // 33,554,432
#define RP_BYTES   ((size_t)D_ * D_ * 2)             // 524,288
#define HBUF_UINTS (2 * B_ * 2 * 256)                // 65,536 (256 KB)
#define PBANK      ((size_t)B_ * 2 * 256)            // uints per parity bank
#define SPIN_CAP   65536

typedef _Float16 half2_t __attribute__((ext_vector_type(2)));
typedef unsigned int uintx4 __attribute__((ext_vector_type(4)));

__device__ __forceinline__ float dot2(unsigned int r, unsigned int h, float acc) {
    return __builtin_amdgcn_fdot2(__builtin_bit_cast(half2_t, h),
                                  __builtin_bit_cast(half2_t, r), acc, false);
}
__device__ __forceinline__ float dot4u(uintx4 r, uintx4 h, float acc) {
    acc = dot2(r.x, h.x, acc);
    acc = dot2(r.y, h.y, acc);
    acc = dot2(r.z, h.z, acc);
    acc = dot2(r.w, h.w, acc);
    return acc;
}
template<int CTRL>
__device__ __forceinline__ float dpp_mov(float v) {
    return __builtin_bit_cast(float, __builtin_amdgcn_update_dpp(
        0, __builtin_bit_cast(int, v), CTRL, 0xF, 0xF, true));
}
// DPP ctrls: 0xB1=xor1, 0x4E=xor2, 0x141=row_half_mirror(xor7),
// 0x140=row_mirror(xor15), 0x142=row_bcast15, 0x143=row_bcast31.

__device__ __forceinline__ unsigned int pk_f16(float a, float b) {
    return __builtin_bit_cast(unsigned int, __builtin_amdgcn_cvt_pkrtz(a, b));
}
__device__ __forceinline__ unsigned int ld_sc01(const unsigned int* p) {
    unsigned int v;
    asm volatile("global_load_dword %0, %1, off sc0 sc1\n\t"
                 "s_waitcnt vmcnt(0)" : "=v"(v) : "v"(p) : "memory");
    return v;
}
__device__ __forceinline__ void st_sc01(unsigned int* p, unsigned int v) {
    asm volatile("global_store_dword %0, %1, off sc0 sc1" :: "v"(p), "v"(v) : "memory");
}
// rotation swizzle over 32 uint4 slots: block b=i>>3 rotates by b
__device__ __forceinline__ int swz4(int i) {
    return ((i >> 3) << 3) | ((i + (i >> 3)) & 7);
}

// 8-chunk dot block: 4 outputs x 4 uint4 of h; rr indices compile-time
template<int BASE>
__device__ __forceinline__ void dots16(const uintx4 (&rr)[32], const uintx4* h4,
        int ri0, int ri1, int ri2, int ri3,
        float& p0, float& p1, float& p2, float& p3) {
    uintx4 h0 = h4[ri0], h1 = h4[ri1], h2 = h4[ri2], h3 = h4[ri3];
    p0 = dot4u(rr[BASE + 0],  h0, p0); p0 = dot4u(rr[BASE + 1],  h1, p0);
    p0 = dot4u(rr[BASE + 2],  h2, p0); p0 = dot4u(rr[BASE + 3],  h3, p0);
    p1 = dot4u(rr[BASE + 4],  h0, p1); p1 = dot4u(rr[BASE + 5],  h1, p1);
    p1 = dot4u(rr[BASE + 6],  h2, p1); p1 = dot4u(rr[BASE + 7],  h3, p1);
    p2 = dot4u(rr[BASE + 8],  h0, p2); p2 = dot4u(rr[BASE + 9],  h1, p2);
    p2 = dot4u(rr[BASE + 10], h2, p2); p2 = dot4u(rr[BASE + 11], h3, p2);
    p3 = dot4u(rr[BASE + 12], h0, p3); p3 = dot4u(rr[BASE + 13], h1, p3);
    p3 = dot4u(rr[BASE + 14], h2, p3); p3 = dot4u(rr[BASE + 15], h3, p3);
}

// Pack R_ig fp32[k][d] -> f16-pair uint chunks, layout [q][m][tid_s][dw]:
// chunk m = hh*16 + j*4 + c of thread tid_s (w,l,r,g) in WG-half q holds
// pairs for output d = q*256 + (w*8+r)*4 + j at
// k0 = hh*256 + (g&3)*64 + (g>>2)*32 + c*8 + 2*dw.
// Also zeroes hbuf (tags!) and out each launch (graph-replay safe).
__global__ __launch_bounds__(256) void prep_kernel(const float* __restrict__ R,
        unsigned int* __restrict__ Rp, unsigned int* __restrict__ hbuf,
        float* __restrict__ out) {
    int id = blockIdx.x * 256 + threadIdx.x;          // 131072 uints
    int dw = id & 3;
    int U = id >> 2;
    int tid_s = U & 511;
    int m  = (U >> 9) & 31;
    int qq = U >> 14;
    int w = tid_s >> 6, l = tid_s & 63, r = l >> 3, g = l & 7;
    int hh = m >> 4, j = (m >> 2) & 3, c = m & 3;
    int d  = qq * 256 + (w * 8 + r) * 4 + j;
    int k0 = hh * 256 + (g & 3) * 64 + (g >> 2) * 32 + c * 8 + 2 * dw;
    half2_t v;
    v.x = (_Float16)R[k0 * D_ + d];
    v.y = (_Float16)R[(k0 + 1) * D_ + d];
    Rp[id] = __builtin_bit_cast(unsigned int, v);
    if (id < HBUF_UINTS) hbuf[id] = 0u;
    if (id < B_ * L_) out[id] = 0.f;
}

// ci = tanh(x @ W_ci + b_ci), stored f16.  One block does CI_R (b,l) rows.
__global__ __launch_bounds__(256) void ci_kernel(const float* __restrict__ obs,
                                                 const float* __restrict__ act,
                                                 const float* __restrict__ W,
                                                 const float* __restrict__ bci,
                                                 unsigned short* __restrict__ ci) {
    __shared__ float xs[CI_R][F_];
    int row0 = blockIdx.x * CI_R;
    int tid = threadIdx.x;
    for (int idx = tid; idx < CI_R * F_; idx += 256) {
        int r = idx / F_, f = idx % F_;
        float v = (f < P_) ? obs[(size_t)(row0 + r) * P_ + f]
                           : act[(size_t)(row0 + r) * A_ + (f - P_)];
        xs[r][f] = v;
    }
    __syncthreads();
    int d0 = tid, d1 = tid + 256;
    float a0[CI_R], a1[CI_R];
    #pragma unroll
    for (int r = 0; r < CI_R; ++r) { a0[r] = 0.f; a1[r] = 0.f; }
    for (int f = 0; f < F_; ++f) {
        float w0 = W[f * D_ + d0];
        float w1 = W[f * D_ + d1];
        #pragma unroll
        for (int r = 0; r < CI_R; ++r) {
            float xv = xs[r][f];
            a0[r] += xv * w0;
            a1[r] += xv * w1;
        }
    }
    float b0 = bci[d0], b1 = bci[d1];
    #pragma unroll
    for (int r = 0; r < CI_R; ++r) {
        float z0 = a0[r] + b0, z1 = a1[r] + b1;
        float e0 = __expf(-2.f * __builtin_fabsf(z0));
        float e1 = __expf(-2.f * __builtin_fabsf(z1));
        float m0 = (1.f - e0) * __builtin_amdgcn_rcpf(1.f + e0);
        float m1 = (1.f - e1) * __builtin_amdgcn_rcpf(1.f + e1);
        float t0 = z0 < 0.f ? -m0 : m0;
        float t1 = z1 < 0.f ? -m1 : m1;
        ci[(size_t)(row0 + r) * D_ + d0] = __builtin_bit_cast(unsigned short, (_Float16)t0);
        ci[(size_t)(row0 + r) * D_ + d1] = __builtin_bit_cast(unsigned short, (_Float16)t1);
    }
}

// Serial scan, row-pair per WG-pair.  WG (pr=bid&31, q=bid>>5) handles
// rows 2pr, 2pr+1, owns d in [q*256,+256) for both.  Thread (w,l,r,g):
// 4 outputs d = q*256+(w*8+r)*4+j per row; k-partition split own/remote
// (as R12).  All 512 threads fetch one tagged dword: tid<256 row A,
// tid>=256 row B.  One A/B barrier pair serves both rows per step.
__global__ __launch_bounds__(512, 2)
__attribute__((amdgpu_waves_per_eu(2, 2)))
void scan_kernel(const unsigned int* __restrict__ Rp,
                 const unsigned short* __restrict__ ci,
                 const float* __restrict__ b_ig, const float* __restrict__ W_out,
                 const float* __restrict__ b_out, float* __restrict__ out,
                 unsigned int* __restrict__ hbuf)
{
    const int tid = threadIdx.x;
    const int bid = blockIdx.x;
    const int pr  = bid & 31;          // bid, bid+32 same XCD (32%8==0)
    const int q   = bid >> 5;
    const int rowA = pr * 2;
    const int rowB = pr * 2 + 1;
    const int w = tid >> 6;
    const int l = tid & 63;
    const int r = l >> 3;
    const int g = l & 7;
    const int g3 = g & 3;

    __shared__ __align__(16) unsigned int hp2A[128], hp2B[128];  // own-half pairs
    __shared__ __align__(16) unsigned int hstA[128], hstB[128];  // remote-half pairs

    // rr pre-swapped: rr[mm] = chunk (mm ^ (q<<4)) -> rr[0..15] own half
    const uintx4* tb = (const uintx4*)Rp + (size_t)q * 16384 + tid;
    const int qx = q << 4;
    uintx4 rr[32];
    #pragma unroll
    for (int mm = 0; mm < 32; ++mm) rr[mm] = tb[(mm ^ qx) * 512];
    #pragma unroll
    for (int mm = 0; mm < 32; ++mm) asm volatile("" : "+v"(rr[mm]));

    const int dloc = (w * 8 + r) * 4 + g3;
    const int down = q * 256 + dloc;
    const float bg = b_ig[down];
    const float wo = W_out[down];
    const float bo = b_out[0];
    const unsigned short* cipA = ci + (size_t)rowA * L_ * D_ + down;
    const unsigned short* cipB = ci + (size_t)rowB * L_ * D_ + down;

    // hp2 writer slot (lanes g in {0,2}): pair u = (w*8+r)*2 + (g>>1)
    const int u_own = (w * 8 + r) * 2 + (g >> 1);
    const int wslot = swz4(u_own >> 2) * 4 + (u_own & 3);
    // fetcher: s_f = tid&255, srow by tid>>8; even s_f writes packed dword
    const int s_f = tid & 255;
    const int stslot = swz4(s_f >> 3) * 4 + ((s_f >> 1) & 3);
    // h-read uint4 base index: i = (g&3)*8 + (g>>2)*4 + c
    const int ib = (g & 3) * 8 + (g >> 2) * 4;
    const int ri0 = swz4(ib + 0), ri1 = swz4(ib + 1);
    const int ri2 = swz4(ib + 2), ri3 = swz4(ib + 3);

    const int srow = (tid >> 8) ? rowB : rowA;
    const unsigned int* rdbase = hbuf + ((size_t)srow * 2 + (1 - q)) * 256 + s_f;
    unsigned int* wrA = hbuf + ((size_t)rowA * 2 + q) * 256 + dloc;
    unsigned int* wrB = hbuf + ((size_t)rowB * 2 + q) * 256 + dloc;
    unsigned int* hstMine = (tid >> 8) ? hstB : hstA;

    float hvalA = 0.f, hvalB = 0.f;
    __syncthreads();

    #pragma unroll 1
    for (int t = 0; t < L_; ++t) {
        unsigned short cuA = cipA[(size_t)t * D_];   // issue early
        unsigned short cuB = cipB[(size_t)t * D_];

        // issue tagged fetch (no wait) -- ages during both rows' own-dots
        unsigned int vfetch = 0;
        const unsigned int* src = rdbase + (size_t)((t - 1) & 1) * PBANK;
        if (t > 0) {
            asm volatile("global_load_dword %0, %1, off sc0 sc1"
                         : "=&v"(vfetch) : "v"(src) : "memory");
        }

        float pA0 = 0.f, pA1 = 0.f, pA2 = 0.f, pA3 = 0.f;
        float pB0 = 0.f, pB1 = 0.f, pB2 = 0.f, pB3 = 0.f;

        // phase2: own-half dots, rows A then B (fetch in flight)
        if (t > 0) {
            dots16<0>(rr, (const uintx4*)hp2A, ri0, ri1, ri2, ri3, pA0, pA1, pA2, pA3);
            dots16<0>(rr, (const uintx4*)hp2B, ri0, ri1, ri2, ri3, pB0, pB1, pB2, pB3);
        }

        // phase3: finish fetch; serial retry if stale; stage into hst{A,B}
        if (t > 0) {
            asm volatile("s_waitcnt vmcnt(0)" : "+v"(vfetch) :: "memory");
            const unsigned int tt = (unsigned int)t;
            int it = 0;
            while ((vfetch & 0xffffu) != tt) {
                if (++it > SPIN_CAP) break;            // finite fail, no hang
                if (it > 1) __builtin_amdgcn_s_sleep(1);
                vfetch = ld_sc01(src);
            }
            unsigned int vo = __builtin_bit_cast(unsigned int,
                                dpp_mov<0xB1>(__builtin_bit_cast(float, vfetch)));
            if ((s_f & 1) == 0)
                hstMine[stslot] = (vfetch >> 16) | (vo & 0xffff0000u);
        }

        // barrier A: hst visible; separates phase2 reads from hp2 rewrite
        asm volatile("s_waitcnt lgkmcnt(0)" ::: "memory");
        __builtin_amdgcn_s_barrier();
        asm volatile("" ::: "memory");

        // phase5: remote-half dots, rows A then B
        if (t > 0) {
            dots16<16>(rr, (const uintx4*)hstA, ri0, ri1, ri2, ri3, pA0, pA1, pA2, pA3);
            dots16<16>(rr, (const uintx4*)hstB, ri0, ri1, ri2, ri3, pB0, pB1, pB2, pB3);
        }

        // 8-lane full reduce (xor7, xor1, xor2) per accumulator, both rows
        float sA0 = pA0 + dpp_mov<0x141>(pA0);
        float sA1 = pA1 + dpp_mov<0x141>(pA1);
        float sA2 = pA2 + dpp_mov<0x141>(pA2);
        float sA3 = pA3 + dpp_mov<0x141>(pA3);
        float sB0 = pB0 + dpp_mov<0x141>(pB0);
        float sB1 = pB1 + dpp_mov<0x141>(pB1);
        float sB2 = pB2 + dpp_mov<0x141>(pB2);
        float sB3 = pB3 + dpp_mov<0x141>(pB3);
        sA0 = sA0 + dpp_mov<0xB1>(sA0);  sA1 = sA1 + dpp_mov<0xB1>(sA1);
        sA2 = sA2 + dpp_mov<0xB1>(sA2);  sA3 = sA3 + dpp_mov<0xB1>(sA3);
        sB0 = sB0 + dpp_mov<0xB1>(sB0);  sB1 = sB1 + dpp_mov<0xB1>(sB1);
        sB2 = sB2 + dpp_mov<0xB1>(sB2);  sB3 = sB3 + dpp_mov<0xB1>(sB3);
        sA0 = sA0 + dpp_mov<0x4E>(sA0);  sA1 = sA1 + dpp_mov<0x4E>(sA1);
        sA2 = sA2 + dpp_mov<0x4E>(sA2);  sA3 = sA3 + dpp_mov<0x4E>(sA3);
        sB0 = sB0 + dpp_mov<0x4E>(sB0);  sB1 = sB1 + dpp_mov<0x4E>(sB1);
        sB2 = sB2 + dpp_mov<0x4E>(sB2);  sB3 = sB3 + dpp_mov<0x4E>(sB3);
        float zA = ((g3 & 2) ? ((g3 & 1) ? sA3 : sA2)
                             : ((g3 & 1) ? sA1 : sA0)) + bg;
        float zB = ((g3 & 2) ? ((g3 & 1) ? sB3 : sB2)
                             : ((g3 & 1) ? sB1 : sB0)) + bg;

        float igA  = __builtin_amdgcn_rcpf(1.f + __expf(-zA));
        float igB  = __builtin_amdgcn_rcpf(1.f + __expf(-zB));
        hvalA += (float)__builtin_bit_cast(_Float16, cuA) * igA;
        hvalB += (float)__builtin_bit_cast(_Float16, cuB) * igB;

        // publish tagged h IMMEDIATELY, both rows (g<4)
        if (g < 4) {
            unsigned int tag = (unsigned int)(t + 1);
            st_sc01(wrA + (size_t)(t & 1) * PBANK,
                    ((pk_f16(hvalA, hvalA) & 0xffffu) << 16) | tag);
            st_sc01(wrB + (size_t)(t & 1) * PBANK,
                    ((pk_f16(hvalB, hvalB) & 0xffffu) << 16) | tag);
        }

        // own-half pair publish to hp2, both rows (writers g in {0,2})
        float nbhA = dpp_mov<0xB1>(hvalA);
        float nbhB = dpp_mov<0xB1>(hvalB);
        if (g == 0 || g == 2) {
            hp2A[wslot] = pk_f16(hvalA, nbhA);
            hp2B[wslot] = pk_f16(hvalB, nbhB);
        }

        // barrier B: hp2 writes ordered before next step's phase2 reads
        asm volatile("s_waitcnt lgkmcnt(0)" ::: "memory");
        __builtin_amdgcn_s_barrier();
        asm volatile("" ::: "memory");

        // out[t] commits, post-B (off the critical chain)
        float poA = (g < 4) ? hvalA * wo : 0.f;
        float poB = (g < 4) ? hvalB * wo : 0.f;
        poA += dpp_mov<0xB1>(poA);   poB += dpp_mov<0xB1>(poB);
        poA += dpp_mov<0x4E>(poA);   poB += dpp_mov<0x4E>(poB);
        poA += dpp_mov<0x141>(poA);  poB += dpp_mov<0x141>(poB);
        poA += dpp_mov<0x140>(poA);  poB += dpp_mov<0x140>(poB);
        poA += dpp_mov<0x142>(poA);  poB += dpp_mov<0x142>(poB);
        poA += dpp_mov<0x143>(poA);  poB += dpp_mov<0x143>(poB);
        if (l == 63) {
            float ex = (q == 0 && w == 0) ? bo : 0.f;
            atomicAdd(out + rowA * L_ + t, poA + ex);
            atomicAdd(out + rowB * L_ + t, poB + ex);
        }
    }
}

extern "C" void kernel_launch(void* const* d_in, const int* in_sizes, int n_in,
                              void* d_out, int out_size, void* d_ws, size_t ws_size,
                              hipStream_t stream) {
    const float* obs   = (const float*)d_in[0];
    const float* act   = (const float*)d_in[1];
    const float* W_ci  = (const float*)d_in[2];
    const float* b_ci  = (const float*)d_in[3];
    const float* R_ig  = (const float*)d_in[4];
    const float* b_ig  = (const float*)d_in[5];
    const float* W_out = (const float*)d_in[6];
    const float* b_out = (const float*)d_in[7];
    float* out = (float*)d_out;

    unsigned short* ci = (unsigned short*)d_ws;
    unsigned int* Rp   = (unsigned int*)((char*)d_ws + CI_BYTES);
    unsigned int* hbuf = (unsigned int*)((char*)d_ws + CI_BYTES + RP_BYTES);

    prep_kernel<<<512, 256, 0, stream>>>(R_ig, Rp, hbuf, out);
    ci_kernel<<<(B_ * L_) / CI_R, 256, 0, stream>>>(obs, act, W_ci, b_ci, ci);
    scan_kernel<<<B_, 512, 0, stream>>>(Rp, ci, b_ig, W_out, b_out, out, hbuf);
}

// Round 10
// 616.093 us; speedup vs baseline: 1.8620x; 1.8620x over previous
//
#include <hip/hip_runtime.h>

// Custom LSTM scan.  B=64, L=512, P=64, A=16, D=512, F=80.
//   h_t = h_{t-1} + tanh(x_t W_ci + b_ci) * sigmoid(h_{t-1} R_ig + b_ig)
//
// R15 = R13 (best passing: scan 566us) with ONE change: the tagged-h
// publish uses GLOBAL_ATOMIC_SWAP (sc1, agent scope, no-return) instead
// of a plain sc0sc1 store.  R14's row-pair fold regressed 1.85x and
// taught the real model: wall-clock = per-row period T = V + C', with
// V ~2200cy exchange visibility and C' ~400cy; rows are already all
// parallel, so only shrinking T helps.  Hypothesis under test: V is the
// plain-store write-through/invalidation path, not the LLC RT; atomics
// execute AT the coherence point (~300cy after issue) and should cut V
// to ~one poll RT.  Everything else (NQ=2 split, register-resident R,
// split-k own/remote, A/B barriers, batched poll, post-B out commit) is
// R13 verbatim.

#define B_  64
#define L_  512
#define P_  64
#define A_  16
#define D_  512
#define F_  80
#define CI_R 8

#define CI_BYTES   ((size_t)B_ * L_ * D_ * 2)        // 33,554,432
#define RP_BYTES   ((size_t)D_ * D_ * 2)             // 524,288
#define HBUF_UINTS (2 * B_ * 2 * 256)                // 65,536 (256 KB)
#define PBANK      ((size_t)B_ * 2 * 256)            // uints per parity bank
#define BATCH_CAP  4096

typedef _Float16 half2_t __attribute__((ext_vector_type(2)));
typedef unsigned int uintx4 __attribute__((ext_vector_type(4)));

__device__ __forceinline__ float dot2(unsigned int r, unsigned int h, float acc) {
    return __builtin_amdgcn_fdot2(__builtin_bit_cast(half2_t, h),
                                  __builtin_bit_cast(half2_t, r), acc, false);
}
__device__ __forceinline__ float dot4u(uintx4 r, uintx4 h, float acc) {
    acc = dot2(r.x, h.x, acc);
    acc = dot2(r.y, h.y, acc);
    acc = dot2(r.z, h.z, acc);
    acc = dot2(r.w, h.w, acc);
    return acc;
}
template<int CTRL>
__device__ __forceinline__ float dpp_mov(float v) {
    return __builtin_bit_cast(float, __builtin_amdgcn_update_dpp(
        0, __builtin_bit_cast(int, v), CTRL, 0xF, 0xF, true));
}
// DPP ctrls: 0xB1=xor1, 0x4E=xor2, 0x141=row_half_mirror(xor7),
// 0x140=row_mirror(xor15), 0x142=row_bcast15, 0x143=row_bcast31.

__device__ __forceinline__ unsigned int pk_f16(float a, float b) {
    return __builtin_bit_cast(unsigned int, __builtin_amdgcn_cvt_pkrtz(a, b));
}
__device__ __forceinline__ unsigned int ld_sc01(const unsigned int* p) {
    unsigned int v;
    asm volatile("global_load_dword %0, %1, off sc0 sc1\n\t"
                 "s_waitcnt vmcnt(0)" : "=v"(v) : "v"(p) : "memory");
    return v;
}
// publish via atomic swap: executes AT the coherence point (agent scope,
// sc1 = cross-XCD coherent; no sc0 -> no return value, fire-and-forget)
__device__ __forceinline__ void at_swap(unsigned int* p, unsigned int v) {
    asm volatile("global_atomic_swap %0, %1, off sc1" :: "v"(p), "v"(v) : "memory");
}
// rotation swizzle over 32 uint4 slots: block b=i>>3 rotates by b
__device__ __forceinline__ int swz4(int i) {
    return ((i >> 3) << 3) | ((i + (i >> 3)) & 7);
}

// Pack R_ig fp32[k][d] -> f16-pair uint chunks, layout [q][m][tid_s][dw]:
// chunk m = hh*16 + j*4 + c of thread tid_s (w,l,r,g) in WG-half q holds
// pairs for output d = q*256 + (w*8+r)*4 + j at
// k0 = hh*256 + (g&3)*64 + (g>>2)*32 + c*8 + 2*dw.
// Also zeroes hbuf (tags!) and out each launch (graph-replay safe).
__global__ __launch_bounds__(256) void prep_kernel(const float* __restrict__ R,
        unsigned int* __restrict__ Rp, unsigned int* __restrict__ hbuf,
        float* __restrict__ out) {
    int id = blockIdx.x * 256 + threadIdx.x;          // 131072 uints
    int dw = id & 3;
    int U = id >> 2;
    int tid_s = U & 511;
    int m  = (U >> 9) & 31;
    int qq = U >> 14;
    int w = tid_s >> 6, l = tid_s & 63, r = l >> 3, g = l & 7;
    int hh = m >> 4, j = (m >> 2) & 3, c = m & 3;
    int d  = qq * 256 + (w * 8 + r) * 4 + j;
    int k0 = hh * 256 + (g & 3) * 64 + (g >> 2) * 32 + c * 8 + 2 * dw;
    half2_t v;
    v.x = (_Float16)R[k0 * D_ + d];
    v.y = (_Float16)R[(k0 + 1) * D_ + d];
    Rp[id] = __builtin_bit_cast(unsigned int, v);
    if (id < HBUF_UINTS) hbuf[id] = 0u;
    if (id < B_ * L_) out[id] = 0.f;
}

// ci = tanh(x @ W_ci + b_ci), stored f16.  One block does CI_R (b,l) rows.
__global__ __launch_bounds__(256) void ci_kernel(const float* __restrict__ obs,
                                                 const float* __restrict__ act,
                                                 const float* __restrict__ W,
                                                 const float* __restrict__ bci,
                                                 unsigned short* __restrict__ ci) {
    __shared__ float xs[CI_R][F_];
    int row0 = blockIdx.x * CI_R;
    int tid = threadIdx.x;
    for (int idx = tid; idx < CI_R * F_; idx += 256) {
        int r = idx / F_, f = idx % F_;
        float v = (f < P_) ? obs[(size_t)(row0 + r) * P_ + f]
                           : act[(size_t)(row0 + r) * A_ + (f - P_)];
        xs[r][f] = v;
    }
    __syncthreads();
    int d0 = tid, d1 = tid + 256;
    float a0[CI_R], a1[CI_R];
    #pragma unroll
    for (int r = 0; r < CI_R; ++r) { a0[r] = 0.f; a1[r] = 0.f; }
    for (int f = 0; f < F_; ++f) {
        float w0 = W[f * D_ + d0];
        float w1 = W[f * D_ + d1];
        #pragma unroll
        for (int r = 0; r < CI_R; ++r) {
            float xv = xs[r][f];
            a0[r] += xv * w0;
            a1[r] += xv * w1;
        }
    }
    float b0 = bci[d0], b1 = bci[d1];
    #pragma unroll
    for (int r = 0; r < CI_R; ++r) {
        float z0 = a0[r] + b0, z1 = a1[r] + b1;
        float e0 = __expf(-2.f * __builtin_fabsf(z0));
        float e1 = __expf(-2.f * __builtin_fabsf(z1));
        float m0 = (1.f - e0) * __builtin_amdgcn_rcpf(1.f + e0);
        float m1 = (1.f - e1) * __builtin_amdgcn_rcpf(1.f + e1);
        float t0 = z0 < 0.f ? -m0 : m0;
        float t1 = z1 < 0.f ? -m1 : m1;
        ci[(size_t)(row0 + r) * D_ + d0] = __builtin_bit_cast(unsigned short, (_Float16)t0);
        ci[(size_t)(row0 + r) * D_ + d1] = __builtin_bit_cast(unsigned short, (_Float16)t1);
    }
}

// Serial scan, 2 WGs per batch row.  WG (row,q) owns d in [q*256,+256).
// Thread (w,l,r,g): 4 outputs d = q*256+(w*8+r)*4+j; partials over
// k in [hh*256+(g&3)*64+(g>>2)*32, +32) for hh=q (phase2, hp2) and
// hh=1-q (phase5, hst).  8-lane DPP full reduce; lane owns j=g&3.
// rr[0..15]=own-half chunks, rr[16..31]=remote (pre-swapped by q).
__global__ __launch_bounds__(512, 2)
__attribute__((amdgpu_waves_per_eu(2, 2)))
void scan_kernel(const unsigned int* __restrict__ Rp,
                 const unsigned short* __restrict__ ci,
                 const float* __restrict__ b_ig, const float* __restrict__ W_out,
                 const float* __restrict__ b_out, float* __restrict__ out,
                 unsigned int* __restrict__ hbuf)
{
    const int tid = threadIdx.x;
    const int bid = blockIdx.x;
    const int row = bid & 63;
    const int q   = bid >> 6;
    const int w = tid >> 6;
    const int l = tid & 63;
    const int r = l >> 3;
    const int g = l & 7;
    const int g3 = g & 3;

    __shared__ __align__(16) unsigned int hp2[128];   // own-half h pairs, swizzled
    __shared__ __align__(16) unsigned int hst[128];   // remote-half h pairs, swizzled

    // rr pre-swapped: rr[mm] = chunk (mm ^ (q<<4)) -> rr[0..15] own half
    const uintx4* tb = (const uintx4*)Rp + (size_t)q * 16384 + tid;
    const int qx = q << 4;
    uintx4 rr[32];
    #pragma unroll
    for (int mm = 0; mm < 32; ++mm) rr[mm] = tb[(mm ^ qx) * 512];
    #pragma unroll
    for (int mm = 0; mm < 32; ++mm) asm volatile("" : "+v"(rr[mm]));

    const int dloc = (w * 8 + r) * 4 + g3;
    const int down = q * 256 + dloc;
    const float bg = b_ig[down];
    const float wo = W_out[down];
    const float bo = b_out[0];
    const unsigned short* cip = ci + (size_t)row * L_ * D_ + down;

    // hp2 writer slot (lanes g in {0,2}): pair u = (w*8+r)*2 + (g>>1)
    const int u_own = (w * 8 + r) * 2 + (g >> 1);
    const int wslot = swz4(u_own >> 2) * 4 + (u_own & 3);
    // hst fetcher slot: s=tid<256, pair u=s>>1, even lanes write packed dword
    const int s_f = tid & 255;
    const int stslot = swz4(s_f >> 3) * 4 + ((s_f >> 1) & 3);
    // h-read uint4 base index: i = (g&3)*8 + (g>>2)*4 + c
    const int ib = (g & 3) * 8 + (g >> 2) * 4;
    const int ri0 = swz4(ib + 0), ri1 = swz4(ib + 1);
    const int ri2 = swz4(ib + 2), ri3 = swz4(ib + 3);

    const unsigned int* rdbase = hbuf + ((size_t)row * 2 + (1 - q)) * 256 + s_f;
    unsigned int* wrbase = hbuf + ((size_t)row * 2 + q) * 256 + dloc;

    float hval = 0.f;
    __syncthreads();

    #pragma unroll 1
    for (int t = 0; t < L_; ++t) {
        unsigned short cu = cip[(size_t)t * D_];   // issue early

        // issue tagged fetch (no wait) -- RT overlaps own-half dots
        unsigned int vfetch = 0;
        const unsigned int* src = rdbase + (size_t)((t - 1) & 1) * PBANK;
        if (t > 0 && tid < 256) {
            asm volatile("global_load_dword %0, %1, off sc0 sc1"
                         : "=&v"(vfetch) : "v"(src) : "memory");
        }

        float p0 = 0.f, p1 = 0.f, p2 = 0.f, p3 = 0.f;

        // phase2: own-half dots from hp2 (written at tail(t-1), behind B)
        if (t > 0) {
            const uintx4* hp4 = (const uintx4*)hp2;
            uintx4 h0 = hp4[ri0], h1 = hp4[ri1], h2 = hp4[ri2], h3 = hp4[ri3];
            p0 = dot4u(rr[0],  h0, p0); p0 = dot4u(rr[1],  h1, p0);
            p0 = dot4u(rr[2],  h2, p0); p0 = dot4u(rr[3],  h3, p0);
            p1 = dot4u(rr[4],  h0, p1); p1 = dot4u(rr[5],  h1, p1);
            p1 = dot4u(rr[6],  h2, p1); p1 = dot4u(rr[7],  h3, p1);
            p2 = dot4u(rr[8],  h0, p2); p2 = dot4u(rr[9],  h1, p2);
            p2 = dot4u(rr[10], h2, p2); p2 = dot4u(rr[11], h3, p2);
            p3 = dot4u(rr[12], h0, p3); p3 = dot4u(rr[13], h1, p3);
            p3 = dot4u(rr[14], h2, p3); p3 = dot4u(rr[15], h3, p3);
        }

        // phase3: finish fetch; if stale, batched pipelined poll (3 loads
        // spaced by s_sleep, checked oldest-first via vmcnt(2/1/0)).
        if (t > 0 && tid < 256) {
            asm volatile("s_waitcnt vmcnt(0)" : "+v"(vfetch) :: "memory");
            const unsigned int tt = (unsigned int)t;
            if ((vfetch & 0xffffu) != tt) {
                int it = 0;
                unsigned int a0, a1, a2;
                for (;;) {
                    asm volatile("global_load_dword %0, %1, off sc0 sc1"
                                 : "=&v"(a0) : "v"(src) : "memory");
                    __builtin_amdgcn_s_sleep(1);
                    asm volatile("global_load_dword %0, %1, off sc0 sc1"
                                 : "=&v"(a1) : "v"(src) : "memory");
                    __builtin_amdgcn_s_sleep(1);
                    asm volatile("global_load_dword %0, %1, off sc0 sc1"
                                 : "=&v"(a2) : "v"(src) : "memory");
                    asm volatile("s_waitcnt vmcnt(2)" ::: "memory");
                    if ((a0 & 0xffffu) == tt) {
                        vfetch = a0;
                        asm volatile("s_waitcnt vmcnt(0)" ::: "memory");
                        break;
                    }
                    asm volatile("s_waitcnt vmcnt(1)" ::: "memory");
                    if ((a1 & 0xffffu) == tt) {
                        vfetch = a1;
                        asm volatile("s_waitcnt vmcnt(0)" ::: "memory");
                        break;
                    }
                    asm volatile("s_waitcnt vmcnt(0)" ::: "memory");
                    if ((a2 & 0xffffu) == tt) { vfetch = a2; break; }
                    if (++it > BATCH_CAP) break;       // finite fail, no hang
                    __builtin_amdgcn_s_sleep(1);
                }
            }
            unsigned int vo = __builtin_bit_cast(unsigned int,
                                dpp_mov<0xB1>(__builtin_bit_cast(float, vfetch)));
            if ((tid & 1) == 0)
                hst[stslot] = (vfetch >> 16) | (vo & 0xffff0000u);
        }

        // barrier A: hst visible; separates phase2 reads from hp2 rewrite
        asm volatile("s_waitcnt lgkmcnt(0)" ::: "memory");
        __builtin_amdgcn_s_barrier();
        asm volatile("" ::: "memory");

        // phase5: remote-half dots from hst
        if (t > 0) {
            const uintx4* hs4 = (const uintx4*)hst;
            uintx4 h0 = hs4[ri0], h1 = hs4[ri1], h2 = hs4[ri2], h3 = hs4[ri3];
            p0 = dot4u(rr[16], h0, p0); p0 = dot4u(rr[17], h1, p0);
            p0 = dot4u(rr[18], h2, p0); p0 = dot4u(rr[19], h3, p0);
            p1 = dot4u(rr[20], h0, p1); p1 = dot4u(rr[21], h1, p1);
            p1 = dot4u(rr[22], h2, p1); p1 = dot4u(rr[23], h3, p1);
            p2 = dot4u(rr[24], h0, p2); p2 = dot4u(rr[25], h1, p2);
            p2 = dot4u(rr[26], h2, p2); p2 = dot4u(rr[27], h3, p2);
            p3 = dot4u(rr[28], h0, p3); p3 = dot4u(rr[29], h1, p3);
            p3 = dot4u(rr[30], h2, p3); p3 = dot4u(rr[31], h3, p3);
        }

        // 8-lane full reduce (xor7, xor1, xor2) per accumulator
        float s0 = p0 + dpp_mov<0x141>(p0);
        float s1 = p1 + dpp_mov<0x141>(p1);
        float s2 = p2 + dpp_mov<0x141>(p2);
        float s3 = p3 + dpp_mov<0x141>(p3);
        s0 = s0 + dpp_mov<0xB1>(s0);  s1 = s1 + dpp_mov<0xB1>(s1);
        s2 = s2 + dpp_mov<0xB1>(s2);  s3 = s3 + dpp_mov<0xB1>(s3);
        s0 = s0 + dpp_mov<0x4E>(s0);  s1 = s1 + dpp_mov<0x4E>(s1);
        s2 = s2 + dpp_mov<0x4E>(s2);  s3 = s3 + dpp_mov<0x4E>(s3);
        float z = ((g3 & 2) ? ((g3 & 1) ? s3 : s2)
                            : ((g3 & 1) ? s1 : s0)) + bg;

        float ig  = __builtin_amdgcn_rcpf(1.f + __expf(-z));
        float civ = (float)__builtin_bit_cast(_Float16, cu);
        hval += civ * ig;

        // publish tagged h IMMEDIATELY via atomic swap (g<4) -- lands at
        // the coherence point without the store write-through path
        if (g < 4) {
            unsigned int hb = pk_f16(hval, hval) & 0xffffu;
            at_swap(wrbase + (size_t)(t & 1) * PBANK,
                    (hb << 16) | (unsigned int)(t + 1));
        }

        // own-half pair publish to hp2 (writers g in {0,2})
        float nbh = dpp_mov<0xB1>(hval);   // lane^1 = odd-d neighbor
        if (g == 0 || g == 2) {
            hp2[wslot] = pk_f16(hval, nbh);
        }

        // barrier B: hp2 writes ordered before next step's phase2 reads
        asm volatile("s_waitcnt lgkmcnt(0)" ::: "memory");
        __builtin_amdgcn_s_barrier();
        asm volatile("" ::: "memory");

        // out[t] commit, post-B (off the critical chain)
        float po = (g < 4) ? hval * wo : 0.f;
        po += dpp_mov<0xB1>(po);
        po += dpp_mov<0x4E>(po);
        po += dpp_mov<0x141>(po);
        po += dpp_mov<0x140>(po);
        po += dpp_mov<0x142>(po);
        po += dpp_mov<0x143>(po);
        if (l == 63) {
            float addv = po + ((q == 0 && w == 0) ? bo : 0.f);
            atomicAdd(out + row * L_ + t, addv);
        }
    }
}

extern "C" void kernel_launch(void* const* d_in, const int* in_sizes, int n_in,
                              void* d_out, int out_size, void* d_ws, size_t ws_size,
                              hipStream_t stream) {
    const float* obs   = (const float*)d_in[0];
    const float* act   = (const float*)d_in[1];
    const float* W_ci  = (const float*)d_in[2];
    const float* b_ci  = (const float*)d_in[3];
    const float* R_ig  = (const float*)d_in[4];
    const float* b_ig  = (const float*)d_in[5];
    const float* W_out = (const float*)d_in[6];
    const float* b_out = (const float*)d_in[7];
    float* out = (float*)d_out;

    unsigned short* ci = (unsigned short*)d_ws;
    unsigned int* Rp   = (unsigned int*)((char*)d_ws + CI_BYTES);
    unsigned int* hbuf = (unsigned int*)((char*)d_ws + CI_BYTES + RP_BYTES);

    prep_kernel<<<512, 256, 0, stream>>>(R_ig, Rp, hbuf, out);
    ci_kernel<<<(B_ * L_) / CI_R, 256, 0, stream>>>(obs, act, W_ci, b_ci, ci);
    scan_kernel<<<B_ * 2, 512, 0, stream>>>(Rp, ci, b_ig, W_out, b_out, out, hbuf);
}